// Round 1
// baseline (1047.623 us; speedup 1.0000x reference)
//
#include <hip/hip_runtime.h>
#include <stdint.h>

#define E 128
#define W 64
#define C 1024
#define S 8
#define NBUCK 4096

__device__ __forceinline__ float sigm(float x) { return 1.0f / (1.0f + expf(-x)); }

// ---------------------------------------------------------------------------
// k_update: (LSTM tail of previous step) + (posterior MLP of this step)
// grid = 64 (one block per beam), block = 256
// ---------------------------------------------------------------------------
__global__ __launch_bounds__(256) void k_update(
    int step,
    const float* __restrict__ ent_emb, const float* __restrict__ rel_emb,
    const float* __restrict__ relation,
    const float* __restrict__ W1, const float* __restrict__ b1,
    const float* __restrict__ W2, const float* __restrict__ b2,
    const float* __restrict__ lstm_k, const float* __restrict__ lstm_r,
    const float* __restrict__ lstm_b,
    const int* __restrict__ cand_rel_ids, const int* __restrict__ cand_ent_ids,
    const int* __restrict__ start_ent,
    const int* __restrict__ parent, const int* __restrict__ sel,
    float* __restrict__ Hbuf, float* __restrict__ Cbuf,   // each 2*W*E
    float* __restrict__ feature)                           // W*2E
{
  const int w = blockIdx.x, t = threadIdx.x;
  __shared__ float x[3 * E];
  __shared__ float hmid[3 * E];
  __shared__ float inp[2 * E];
  __shared__ float hp[E], cp[E];
  __shared__ float z[4 * E];
  __shared__ float hnew[E];
  __shared__ int s_cur;

  float* Hw = Hbuf + (size_t)(step & 1) * W * E;
  float* Cw = Cbuf + (size_t)(step & 1) * W * E;
  const float* Hp = Hbuf + (size_t)((step + 1) & 1) * W * E;
  const float* Cp = Cbuf + (size_t)((step + 1) & 1) * W * E;

  if (step == 0) {
    if (t < E) { hnew[t] = 0.f; Hw[w * E + t] = 0.f; Cw[w * E + t] = 0.f; }
    if (t == 0) s_cur = start_ent[w];
  } else {
    const int p = parent[w], sl = sel[w];
    const int* crp = cand_rel_ids + (size_t)(step - 1) * W * C + (size_t)p * C;
    const int* cep = cand_ent_ids + (size_t)(step - 1) * W * C + (size_t)p * C;
    const int rid = crp[sl], eid = cep[sl];
    if (t < E) {
      inp[t]     = rel_emb[(size_t)rid * E + t];
      inp[E + t] = ent_emb[(size_t)eid * E + t];
      hp[t] = Hp[p * E + t];
      cp[t] = Cp[p * E + t];
    }
    if (t == 0) s_cur = eid;
    __syncthreads();
    for (int j = t; j < 4 * E; j += 256) {
      float acc = lstm_b[j];
      for (int k = 0; k < 2 * E; ++k) acc += inp[k] * lstm_k[k * 4 * E + j];
      for (int k = 0; k < E; ++k)     acc += hp[k] * lstm_r[k * 4 * E + j];
      z[j] = acc;
    }
    __syncthreads();
    if (t < E) {
      const float zi = z[t], zf = z[E + t], zg = z[2 * E + t], zo = z[3 * E + t];
      const float cn = sigm(zf) * cp[t] + sigm(zi) * tanhf(zg);
      const float hn = sigm(zo) * tanhf(cn);
      hnew[t] = hn;
      Hw[w * E + t] = hn;
      Cw[w * E + t] = cn;
    }
  }
  __syncthreads();
  const int cur = s_cur;
  if (t < E) {
    x[t]         = ent_emb[(size_t)cur * E + t];
    x[E + t]     = hnew[t];
    x[2 * E + t] = relation[t];
  }
  __syncthreads();
  for (int j = t; j < 3 * E; j += 256) {
    float acc = b1[j];
    for (int k = 0; k < 3 * E; ++k) acc += x[k] * W1[k * 3 * E + j];
    hmid[j] = fmaxf(acc, 0.f);
  }
  __syncthreads();
  if (t < 2 * E) {
    float acc = b2[t];
    for (int k = 0; k < 3 * E; ++k) acc += hmid[k] * W2[k * 2 * E + t];
    feature[(size_t)w * 2 * E + t] = fmaxf(acc, 0.f);
  }
}

// ---------------------------------------------------------------------------
// k_scores: one candidate per thread. grid = 64*4, block = 256
// ---------------------------------------------------------------------------
__global__ __launch_bounds__(256) void k_scores(
    int step,
    const float* __restrict__ ent_emb, const float* __restrict__ rel_emb,
    const int* __restrict__ cand_rel_ids, const int* __restrict__ cand_ent_ids,
    const float* __restrict__ feature, float* __restrict__ scores)
{
  const int w = blockIdx.x >> 2;
  const int c = ((blockIdx.x & 3) << 8) + threadIdx.x;
  __shared__ float4 f4[64];
  if (threadIdx.x < 64)
    f4[threadIdx.x] = ((const float4*)(feature + (size_t)w * 2 * E))[threadIdx.x];
  __syncthreads();
  const size_t base = (size_t)step * W * C + (size_t)w * C + c;
  const int rid = cand_rel_ids[base], eid = cand_ent_ids[base];
  const float4* rp = (const float4*)(rel_emb + (size_t)rid * E);
  const float4* ep = (const float4*)(ent_emb + (size_t)eid * E);
  float acc = 0.f;
#pragma unroll
  for (int i = 0; i < 32; ++i) {
    const float4 r = rp[i], f = f4[i];
    acc += r.x * f.x + r.y * f.y + r.z * f.z + r.w * f.w;
  }
#pragma unroll
  for (int i = 0; i < 32; ++i) {
    const float4 e = ep[i], f = f4[32 + i];
    acc += e.x * f.x + e.y * f.y + e.z * f.z + e.w * f.w;
  }
  scores[(size_t)w * C + c] = acc;
}

// ---------------------------------------------------------------------------
// k_softrow: softmax + per-row top-64 (histogram threshold + rank-by-count)
// grid = 64, block = 256
// ---------------------------------------------------------------------------
__global__ __launch_bounds__(256) void k_softrow(
    int step, const float* __restrict__ scores, float* __restrict__ out,
    unsigned long long* __restrict__ rowtop)
{
  const int w = blockIdx.x, t = threadIdx.x;
  __shared__ float sc[C];
  __shared__ float red[256];
  __shared__ unsigned long long keys[C];
  __shared__ unsigned int hist[NBUCK];
  __shared__ unsigned long long coll[C];
  __shared__ int s_cnt, s_B;

  for (int i = t; i < C; i += 256) sc[i] = scores[(size_t)w * C + i];
  for (int i = t; i < NBUCK; i += 256) hist[i] = 0;
  __syncthreads();

  float m = -INFINITY;
  for (int i = t; i < C; i += 256) m = fmaxf(m, sc[i]);
  red[t] = m;
  __syncthreads();
  for (int s2 = 128; s2 > 0; s2 >>= 1) {
    if (t < s2) red[t] = fmaxf(red[t], red[t + s2]);
    __syncthreads();
  }
  m = red[0];
  __syncthreads();

  float sum = 0.f;
  for (int i = t; i < C; i += 256) {
    const float p = expf(sc[i] - m);
    sc[i] = p;
    sum += p;
  }
  red[t] = sum;
  __syncthreads();
  for (int s2 = 128; s2 > 0; s2 >>= 1) {
    if (t < s2) red[t] += red[t + s2];
    __syncthreads();
  }
  const float inv = 1.f / red[0];
  __syncthreads();

  for (int i = t; i < C; i += 256) {
    const float p = sc[i] * inv;
    out[(size_t)step * W * C + (size_t)w * C + i] = p;
    const unsigned int mono = __float_as_uint(p) | 0x80000000u;
    const unsigned long long key =
        ((unsigned long long)mono << 32) | (unsigned int)~(unsigned)(w * C + i);
    keys[i] = key;
    atomicAdd(&hist[(mono >> 19) & 0xFFFu], 1u);
  }
  __syncthreads();

  // suffix scan (Hillis-Steele)
  for (int off = 1; off < NBUCK; off <<= 1) {
    unsigned tmp[NBUCK / 256];
    for (int i = t, q = 0; i < NBUCK; i += 256, ++q)
      tmp[q] = (i + off < NBUCK) ? hist[i + off] : 0u;
    __syncthreads();
    for (int i = t, q = 0; i < NBUCK; i += 256, ++q) hist[i] += tmp[q];
    __syncthreads();
  }
  for (int i = t; i < NBUCK; i += 256) {
    const unsigned here = hist[i];
    const unsigned nxt = (i + 1 < NBUCK) ? hist[i + 1] : 0u;
    if (here >= 64u && nxt < 64u) s_B = i;
  }
  if (t == 0) s_cnt = 0;
  __syncthreads();

  const int B = s_B;
  for (int i = t; i < C; i += 256) {
    const int b = (int)((keys[i] >> 51) & 0xFFFull);
    if (b >= B) {
      const int p = atomicAdd(&s_cnt, 1);
      coll[p] = keys[i];
    }
  }
  __syncthreads();
  const int M = s_cnt;
  for (int i = t; i < M; i += 256) {
    const unsigned long long ki = coll[i];
    int r = 0;
    for (int j = 0; j < M; ++j) r += (coll[j] > ki);
    if (r < 64) rowtop[(size_t)w * 64 + r] = ki;
  }
}

// ---------------------------------------------------------------------------
// k_topk: global top-64 over 64*64 row winners -> parent/sel
// grid = 1, block = 256
// ---------------------------------------------------------------------------
__global__ __launch_bounds__(256) void k_topk(
    const unsigned long long* __restrict__ rowtop,
    int* __restrict__ parent, int* __restrict__ sel)
{
  const int t = threadIdx.x;
  __shared__ unsigned long long keys[W * 64];
  __shared__ unsigned int hist[NBUCK];
  __shared__ unsigned long long coll[W * 64];
  __shared__ int s_cnt, s_B;

  for (int i = t; i < W * 64; i += 256) keys[i] = rowtop[i];
  for (int i = t; i < NBUCK; i += 256) hist[i] = 0;
  __syncthreads();
  for (int i = t; i < W * 64; i += 256)
    atomicAdd(&hist[(unsigned)(keys[i] >> 51) & 0xFFFu], 1u);
  __syncthreads();

  for (int off = 1; off < NBUCK; off <<= 1) {
    unsigned tmp[NBUCK / 256];
    for (int i = t, q = 0; i < NBUCK; i += 256, ++q)
      tmp[q] = (i + off < NBUCK) ? hist[i + off] : 0u;
    __syncthreads();
    for (int i = t, q = 0; i < NBUCK; i += 256, ++q) hist[i] += tmp[q];
    __syncthreads();
  }
  for (int i = t; i < NBUCK; i += 256) {
    const unsigned here = hist[i];
    const unsigned nxt = (i + 1 < NBUCK) ? hist[i + 1] : 0u;
    if (here >= 64u && nxt < 64u) s_B = i;
  }
  if (t == 0) s_cnt = 0;
  __syncthreads();

  const int B = s_B;
  for (int i = t; i < W * 64; i += 256) {
    const int b = (int)((keys[i] >> 51) & 0xFFFull);
    if (b >= B) {
      const int p = atomicAdd(&s_cnt, 1);
      coll[p] = keys[i];
    }
  }
  __syncthreads();
  const int M = s_cnt;
  for (int i = t; i < M; i += 256) {
    const unsigned long long ki = coll[i];
    int r = 0;
    for (int j = 0; j < M; ++j) r += (coll[j] > ki);
    if (r < 64) {
      const unsigned flat = ~(unsigned)(ki & 0xFFFFFFFFull);
      parent[r] = (int)(flat >> 10);
      sel[r] = (int)(flat & 1023u);
    }
  }
}

// ---------------------------------------------------------------------------
extern "C" void kernel_launch(void* const* d_in, const int* in_sizes, int n_in,
                              void* d_out, int out_size, void* d_ws, size_t ws_size,
                              hipStream_t stream) {
  const float* ent_emb  = (const float*)d_in[0];
  const float* rel_emb  = (const float*)d_in[1];
  const float* relation = (const float*)d_in[2];
  const float* W1 = (const float*)d_in[3];
  const float* b1 = (const float*)d_in[4];
  const float* W2 = (const float*)d_in[5];
  const float* b2 = (const float*)d_in[6];
  const float* lstm_k = (const float*)d_in[7];
  const float* lstm_r = (const float*)d_in[8];
  const float* lstm_b = (const float*)d_in[9];
  const int* cr = (const int*)d_in[10];
  const int* ce = (const int*)d_in[11];
  const int* start_ent = (const int*)d_in[12];
  float* out = (float*)d_out;

  float* feature = (float*)d_ws;                       // W*2E
  float* Hbuf = feature + (size_t)W * 2 * E;           // 2*W*E
  float* Cbuf = Hbuf + (size_t)2 * W * E;              // 2*W*E
  float* scores = Cbuf + (size_t)2 * W * E;            // W*C
  unsigned long long* rowtop = (unsigned long long*)(scores + (size_t)W * C);  // W*64
  int* parent = (int*)(rowtop + (size_t)W * 64);
  int* sel = parent + W;

  for (int s = 0; s < S; ++s) {
    k_update<<<W, 256, 0, stream>>>(s, ent_emb, rel_emb, relation, W1, b1, W2, b2,
                                    lstm_k, lstm_r, lstm_b, cr, ce, start_ent,
                                    parent, sel, Hbuf, Cbuf, feature);
    k_scores<<<W * 4, 256, 0, stream>>>(s, ent_emb, rel_emb, cr, ce, feature, scores);
    k_softrow<<<W, 256, 0, stream>>>(s, scores, out, rowtop);
    if (s < S - 1) k_topk<<<1, 256, 0, stream>>>(rowtop, parent, sel);
  }
}

// Round 2
// 985.355 us; speedup vs baseline: 1.0632x; 1.0632x over previous
//
#include <hip/hip_runtime.h>
#include <stdint.h>

#define E 128
#define W 64
#define C 1024
#define S 8
#define NBUCK 4096

__device__ __forceinline__ float sigm(float x) { return 1.0f / (1.0f + expf(-x)); }

// ---------------------------------------------------------------------------
// k_step: fused (LSTM tail of prev step) + posterior MLP + candidate scoring
//         + softmax + per-row top-64.  grid = 64 (beam per block), block = 1024
// ---------------------------------------------------------------------------
__global__ __launch_bounds__(1024) void k_step(
    int step, int last,
    const float* __restrict__ ent_emb, const float* __restrict__ rel_emb,
    const float* __restrict__ relation,
    const float* __restrict__ W1, const float* __restrict__ b1,
    const float* __restrict__ W2, const float* __restrict__ b2,
    const float* __restrict__ lstm_k, const float* __restrict__ lstm_r,
    const float* __restrict__ lstm_b,
    const int* __restrict__ cand_rel_ids, const int* __restrict__ cand_ent_ids,
    const int* __restrict__ start_ent,
    const int* __restrict__ parent, const int* __restrict__ sel,
    float* __restrict__ Hbuf, float* __restrict__ Cbuf,      // each 2*W*E
    float* __restrict__ out, unsigned long long* __restrict__ rowtop)
{
  const int w = blockIdx.x, t = threadIdx.x;
  __shared__ __align__(16) float x[3 * E];
  __shared__ __align__(16) float hmid[3 * E];
  __shared__ __align__(16) float feat[2 * E];
  __shared__ __align__(16) float inp[2 * E];
  __shared__ float hp[E], cp[E];
  __shared__ float z[4 * E];
  __shared__ float hnew[E];
  __shared__ int s_cur;
  __shared__ float sc[C];
  __shared__ float red[1024];
  __shared__ unsigned long long keys[C];
  __shared__ unsigned int hist[NBUCK];
  __shared__ unsigned long long coll[C];
  __shared__ int s_cnt, s_B;

  float* Hw = Hbuf + (size_t)(step & 1) * W * E;
  float* Cw = Cbuf + (size_t)(step & 1) * W * E;
  const float* Hp = Hbuf + (size_t)((step + 1) & 1) * W * E;
  const float* Cp = Cbuf + (size_t)((step + 1) & 1) * W * E;

  // ---------------- phase A: LSTM state update (prev step's selection) ------
  if (step == 0) {
    if (t < E) { hnew[t] = 0.f; Hw[w * E + t] = 0.f; Cw[w * E + t] = 0.f; }
    if (t == 0) s_cur = start_ent[w];
  } else {
    const int p = parent[w], sl = sel[w];
    const size_t cbase = (size_t)(step - 1) * W * C + (size_t)p * C + sl;
    const int rid = cand_rel_ids[cbase], eid = cand_ent_ids[cbase];
    if (t < E) {
      inp[t]     = rel_emb[(size_t)rid * E + t];
      inp[E + t] = ent_emb[(size_t)eid * E + t];
      hp[t] = Hp[p * E + t];
      cp[t] = Cp[p * E + t];
    }
    if (t == 0) s_cur = eid;
    __syncthreads();
    if (t < 4 * E) {
      float a0 = 0.f, a1 = 0.f, a2 = 0.f, a3 = 0.f;
      const float* K = lstm_k + t;
      for (int k = 0; k < 2 * E; k += 4) {
        a0 += inp[k]     * K[(size_t)(k)     * 4 * E];
        a1 += inp[k + 1] * K[(size_t)(k + 1) * 4 * E];
        a2 += inp[k + 2] * K[(size_t)(k + 2) * 4 * E];
        a3 += inp[k + 3] * K[(size_t)(k + 3) * 4 * E];
      }
      const float* R = lstm_r + t;
      for (int k = 0; k < E; k += 4) {
        a0 += hp[k]     * R[(size_t)(k)     * 4 * E];
        a1 += hp[k + 1] * R[(size_t)(k + 1) * 4 * E];
        a2 += hp[k + 2] * R[(size_t)(k + 2) * 4 * E];
        a3 += hp[k + 3] * R[(size_t)(k + 3) * 4 * E];
      }
      z[t] = lstm_b[t] + ((a0 + a1) + (a2 + a3));
    }
    __syncthreads();
    if (t < E) {
      const float zi = z[t], zf = z[E + t], zg = z[2 * E + t], zo = z[3 * E + t];
      const float cn = sigm(zf) * cp[t] + sigm(zi) * tanhf(zg);
      const float hn = sigm(zo) * tanhf(cn);
      hnew[t] = hn;
      Hw[w * E + t] = hn;
      Cw[w * E + t] = cn;
    }
  }
  __syncthreads();

  // ---------------- phase B: posterior MLP ---------------------------------
  const int cur = s_cur;
  if (t < E) {
    x[t]         = ent_emb[(size_t)cur * E + t];
    x[E + t]     = hnew[t];
    x[2 * E + t] = relation[t];
  }
  __syncthreads();
  if (t < 3 * E) {
    float a0 = 0.f, a1 = 0.f, a2 = 0.f, a3 = 0.f;
    const float* Wp = W1 + t;
    for (int k = 0; k < 3 * E; k += 4) {
      a0 += x[k]     * Wp[(size_t)(k)     * 3 * E];
      a1 += x[k + 1] * Wp[(size_t)(k + 1) * 3 * E];
      a2 += x[k + 2] * Wp[(size_t)(k + 2) * 3 * E];
      a3 += x[k + 3] * Wp[(size_t)(k + 3) * 3 * E];
    }
    hmid[t] = fmaxf(b1[t] + ((a0 + a1) + (a2 + a3)), 0.f);
  }
  __syncthreads();
  if (t < 2 * E) {
    float a0 = 0.f, a1 = 0.f, a2 = 0.f, a3 = 0.f;
    const float* Wp = W2 + t;
    for (int k = 0; k < 3 * E; k += 4) {
      a0 += hmid[k]     * Wp[(size_t)(k)     * 2 * E];
      a1 += hmid[k + 1] * Wp[(size_t)(k + 1) * 2 * E];
      a2 += hmid[k + 2] * Wp[(size_t)(k + 2) * 2 * E];
      a3 += hmid[k + 3] * Wp[(size_t)(k + 3) * 2 * E];
    }
    feat[t] = fmaxf(b2[t] + ((a0 + a1) + (a2 + a3)), 0.f);
  }
  __syncthreads();

  // ---------------- phase C: candidate scoring (1 cand / thread) -----------
  {
    const size_t base = (size_t)step * W * C + (size_t)w * C + t;
    const int rid = cand_rel_ids[base], eid = cand_ent_ids[base];
    const float4* rp = (const float4*)(rel_emb + (size_t)rid * E);
    const float4* ep = (const float4*)(ent_emb + (size_t)eid * E);
    const float4* f4 = (const float4*)feat;
    float ax = 0.f, ay = 0.f, az = 0.f, aw = 0.f;
#pragma unroll
    for (int i = 0; i < 32; ++i) {
      const float4 r = rp[i], f = f4[i];
      ax += r.x * f.x; ay += r.y * f.y; az += r.z * f.z; aw += r.w * f.w;
    }
#pragma unroll
    for (int i = 0; i < 32; ++i) {
      const float4 e = ep[i], f = f4[32 + i];
      ax += e.x * f.x; ay += e.y * f.y; az += e.z * f.z; aw += e.w * f.w;
    }
    sc[t] = (ax + ay) + (az + aw);
  }
  __syncthreads();

  // ---------------- phase D: softmax ----------------------------------------
  red[t] = sc[t];
  __syncthreads();
  for (int s2 = 512; s2 > 0; s2 >>= 1) {
    if (t < s2) red[t] = fmaxf(red[t], red[t + s2]);
    __syncthreads();
  }
  const float m = red[0];
  __syncthreads();
  const float pexp = expf(sc[t] - m);
  red[t] = pexp;
  __syncthreads();
  for (int s2 = 512; s2 > 0; s2 >>= 1) {
    if (t < s2) red[t] += red[t + s2];
    __syncthreads();
  }
  const float prob = pexp * (1.f / red[0]);
  out[(size_t)step * W * C + (size_t)w * C + t] = prob;
  if (last) return;

  // ---------------- phase E: per-row top-64 via 12-bit histogram ------------
  for (int i = t; i < NBUCK; i += 1024) hist[i] = 0;
  const unsigned int mono = __float_as_uint(prob) | 0x80000000u;
  const unsigned long long key =
      ((unsigned long long)mono << 32) | (unsigned int)~(unsigned)(w * C + t);
  keys[t] = key;
  if (t == 0) s_cnt = 0;
  __syncthreads();
  atomicAdd(&hist[(mono >> 19) & 0xFFFu], 1u);
  __syncthreads();
  // suffix scan
  for (int off = 1; off < NBUCK; off <<= 1) {
    unsigned tmp[NBUCK / 1024];
    for (int i = t, q = 0; i < NBUCK; i += 1024, ++q)
      tmp[q] = (i + off < NBUCK) ? hist[i + off] : 0u;
    __syncthreads();
    for (int i = t, q = 0; i < NBUCK; i += 1024, ++q) hist[i] += tmp[q];
    __syncthreads();
  }
  for (int i = t; i < NBUCK; i += 1024) {
    const unsigned here = hist[i];
    const unsigned nxt = (i + 1 < NBUCK) ? hist[i + 1] : 0u;
    if (here >= 64u && nxt < 64u) s_B = i;
  }
  __syncthreads();
  const int B = s_B;
  if ((int)((key >> 51) & 0xFFFull) >= B) {
    const int q = atomicAdd(&s_cnt, 1);
    coll[q] = key;
  }
  __syncthreads();
  const int M = s_cnt;
  for (int i = t; i < M; i += 1024) {
    const unsigned long long ki = coll[i];
    int r = 0;
    for (int j = 0; j < M; ++j) r += (coll[j] > ki);
    if (r < 64) rowtop[(size_t)w * 64 + r] = ki;
  }
}

// ---------------------------------------------------------------------------
// k_topk: global top-64 over 64*64 row winners -> parent/sel
// grid = 1, block = 256
// ---------------------------------------------------------------------------
__global__ __launch_bounds__(256) void k_topk(
    const unsigned long long* __restrict__ rowtop,
    int* __restrict__ parent, int* __restrict__ sel)
{
  const int t = threadIdx.x;
  __shared__ unsigned long long keys[W * 64];
  __shared__ unsigned int hist[NBUCK];
  __shared__ unsigned long long coll[W * 64];
  __shared__ int s_cnt, s_B;

  for (int i = t; i < W * 64; i += 256) keys[i] = rowtop[i];
  for (int i = t; i < NBUCK; i += 256) hist[i] = 0;
  __syncthreads();
  for (int i = t; i < W * 64; i += 256)
    atomicAdd(&hist[(unsigned)(keys[i] >> 51) & 0xFFFu], 1u);
  __syncthreads();

  for (int off = 1; off < NBUCK; off <<= 1) {
    unsigned tmp[NBUCK / 256];
    for (int i = t, q = 0; i < NBUCK; i += 256, ++q)
      tmp[q] = (i + off < NBUCK) ? hist[i + off] : 0u;
    __syncthreads();
    for (int i = t, q = 0; i < NBUCK; i += 256, ++q) hist[i] += tmp[q];
    __syncthreads();
  }
  for (int i = t; i < NBUCK; i += 256) {
    const unsigned here = hist[i];
    const unsigned nxt = (i + 1 < NBUCK) ? hist[i + 1] : 0u;
    if (here >= 64u && nxt < 64u) s_B = i;
  }
  if (t == 0) s_cnt = 0;
  __syncthreads();

  const int B = s_B;
  for (int i = t; i < W * 64; i += 256) {
    const int b = (int)((keys[i] >> 51) & 0xFFFull);
    if (b >= B) {
      const int p = atomicAdd(&s_cnt, 1);
      coll[p] = keys[i];
    }
  }
  __syncthreads();
  const int M = s_cnt;
  for (int i = t; i < M; i += 256) {
    const unsigned long long ki = coll[i];
    int r = 0;
    for (int j = 0; j < M; ++j) r += (coll[j] > ki);
    if (r < 64) {
      const unsigned flat = ~(unsigned)(ki & 0xFFFFFFFFull);
      parent[r] = (int)(flat >> 10);
      sel[r] = (int)(flat & 1023u);
    }
  }
}

// ---------------------------------------------------------------------------
extern "C" void kernel_launch(void* const* d_in, const int* in_sizes, int n_in,
                              void* d_out, int out_size, void* d_ws, size_t ws_size,
                              hipStream_t stream) {
  const float* ent_emb  = (const float*)d_in[0];
  const float* rel_emb  = (const float*)d_in[1];
  const float* relation = (const float*)d_in[2];
  const float* W1 = (const float*)d_in[3];
  const float* b1 = (const float*)d_in[4];
  const float* W2 = (const float*)d_in[5];
  const float* b2 = (const float*)d_in[6];
  const float* lstm_k = (const float*)d_in[7];
  const float* lstm_r = (const float*)d_in[8];
  const float* lstm_b = (const float*)d_in[9];
  const int* cr = (const int*)d_in[10];
  const int* ce = (const int*)d_in[11];
  const int* start_ent = (const int*)d_in[12];
  float* out = (float*)d_out;

  float* Hbuf = (float*)d_ws;                                   // 2*W*E
  float* Cbuf = Hbuf + (size_t)2 * W * E;                       // 2*W*E
  unsigned long long* rowtop = (unsigned long long*)(Cbuf + (size_t)2 * W * E);  // W*64
  int* parent = (int*)(rowtop + (size_t)W * 64);
  int* sel = parent + W;

  for (int s = 0; s < S; ++s) {
    k_step<<<W, 1024, 0, stream>>>(s, (s == S - 1) ? 1 : 0,
                                   ent_emb, rel_emb, relation, W1, b1, W2, b2,
                                   lstm_k, lstm_r, lstm_b, cr, ce, start_ent,
                                   parent, sel, Hbuf, Cbuf, out, rowtop);
    if (s < S - 1) k_topk<<<1, 256, 0, stream>>>(rowtop, parent, sel);
  }
}